// Round 4
// baseline (886.257 us; speedup 1.0000x reference)
//
#include <hip/hip_runtime.h>
#include <math.h>

// Problem constants (fixed by the reference)
#define BN 256     // batch N
#define TT 1000    // timesteps
#define NO 10      // obs dim
#define NS 10      // state dim
#define HID 64     // GRU hidden
#define DIN 20     // NO + NS
#define G3 192     // 3*HID
#define WV 4       // waves per sample (k-split)
#define KW 16      // HID / WV
#define GS 8       // steps per group (1000 = 125 * 8)
#define NG 125     // groups
#define SMP 2      // samples per block

// broadcast lane `l`'s value of v to all lanes (l wave-uniform)
__device__ __forceinline__ float bcast(float v, int l) {
    return __int_as_float(__builtin_amdgcn_readlane(__float_as_int(v), l));
}
__device__ __forceinline__ float rcpf(float x) { return __builtin_amdgcn_rcpf(x); }

// ---------------- Phase 1: GRU recurrence ----------------------------------
// 512-thread blocks = 2 independent samples x 4 waves. Waves 0-3 -> sample A,
// 4-7 -> sample B; wave i sits on SIMD i%4, so each SIMD interleaves one A
// wave with one B wave: B's issue fills A's serial-chain stalls (ds_read
// latency + transcendental chain) and vice versa.
// waves_per_eu(2,2): hard 2 waves/EU -> 256-VGPR budget. R2/R3 capped at 72
// VGPRs and spilled the 79 persistent weight floats; this forces them into
// registers.
// All global I/O batched per 8-step group through LDS (per-step __syncthreads
// emits s_waitcnt vmcnt(0); any in-window global op costs a round-trip/step).
__global__
__attribute__((amdgpu_flat_work_group_size(512, 512), amdgpu_waves_per_eu(2, 2)))
void gru_phase1(const float* __restrict__ Yi, const float* __restrict__ Xh,
                const float* __restrict__ Wi, const float* __restrict__ Wh,
                const float* __restrict__ bi, const float* __restrict__ bh,
                const float* __restrict__ Wmu, const float* __restrict__ Wvar,
                float* __restrict__ mv_out) {
    const int tid = threadIdx.x;
    const int lane = tid & 63;      // hidden unit index
    const int w = tid >> 6;         // wave id 0..7
    const int ws = w & 3;           // wave-within-sample 0..3
    const int sm = w >> 2;          // sample slot 0/1 (compute role)
    const int kb = ws * KW;         // k-range base (hidden)

    // partials: [buf][acc][smp][wave][lane]; accs 0=r 1=z 2=nx 3=nh 4=mv (20.5 KB)
    __shared__ float part[2][5][SMP][WV][HID];
    // input staging: per group, per sample: 160 floats = [y(8x10) | x(8x10)]
    __shared__ float inbuf[2][SMP][GS * DIN];
    // output staging: per group, per sample: 160 floats = [step][20]
    __shared__ float obuf[2][SMP][GS * DIN];

    // ---- staging role (threads 0..319): sample sm2, element lt ----
    const int sm2 = (tid >= 160) ? 1 : 0;
    const int lt = tid - 160 * sm2;
    const bool stg = (tid < 320);
    const int ns = 2 * blockIdx.x + sm2;
    const float* ybase = Yi + (size_t)ns * TT * NO;
    const float* xbase = Xh + (size_t)ns * TT * NS;
    float* obase = mv_out + (size_t)ns * TT * DIN;

    // ---- per-lane weight slices (registers; ~105 VGPRs, fits 256 budget) ----
    float whr[KW], whz[KW], whn[KW], wmv[KW];
    float wir[5], wiz[5], win[5];
#pragma unroll
    for (int k = 0; k < KW; ++k) {
        const int kk = kb + k;
        whr[k] = Wh[kk * G3 + lane];
        whz[k] = Wh[kk * G3 + 64 + lane];
        whn[k] = Wh[kk * G3 + 128 + lane];
        float wm = (lane < NS) ? Wmu[kk * NS + lane] : 0.0f;
        float wv = (lane >= NS && lane < 2 * NS) ? Wvar[kk * NS + (lane - NS)] : 0.0f;
        wmv[k] = wm + wv;   // packed: lanes 0..9 -> W_mu, lanes 10..19 -> W_var
    }
#pragma unroll
    for (int k = 0; k < 5; ++k) {
        const int kk = 5 * ws + k;  // this wave's input dims
        wir[k] = Wi[kk * G3 + lane];
        wiz[k] = Wi[kk * G3 + 64 + lane];
        win[k] = Wi[kk * G3 + 128 + lane];
    }
    const float b_r  = bi[lane] + bh[lane];
    const float b_z  = bi[64 + lane] + bh[64 + lane];
    const float bx_n = bi[128 + lane];
    const float bh_n = bh[128 + lane];

    // LDS offset of this wave's 5 input dims within a step row
    const int ibase = ((ws >= 2) ? 80 : 0) + (ws & 1) * 5;

    // prologue: stage group 0 for both samples
    if (stg)
        inbuf[0][sm2][lt] = (lt < 80) ? ybase[lt] : xbase[lt - 80];
    __syncthreads();

    float h = 0.0f;

#pragma unroll 1
    for (int g = 0; g < NG; ++g) {
        // issue next group's coalesced load (drains at first barrier)
        float ld = 0.0f;
        const bool do_ld = stg && (g + 1 < NG);
        if (do_ld)
            ld = (lt < 80) ? ybase[(size_t)(g + 1) * 80 + lt]
                           : xbase[(size_t)(g + 1) * 80 + (lt - 80)];
        const float* ib = inbuf[g & 1][sm];

#pragma unroll
        for (int s = 0; s < GS; ++s) {
            // ---- pre-barrier: partial sums ----
            const float* ip = ib + ibase + s * 10;
            const float x0 = ip[0], x1 = ip[1], x2 = ip[2], x3 = ip[3], x4 = ip[4];
            float pr = x0 * wir[0], pz = x0 * wiz[0], px = x0 * win[0];
            pr += x1 * wir[1]; pz += x1 * wiz[1]; px += x1 * win[1];
            pr += x2 * wir[2]; pz += x2 * wiz[2]; px += x2 * win[2];
            pr += x3 * wir[3]; pz += x3 * wiz[3]; px += x3 * win[3];
            pr += x4 * wir[4]; pz += x4 * wiz[4]; px += x4 * win[4];
            float pra = 0, prb = 0, pza = 0, pzb = 0;
            float pna = 0, pnb = 0, pma = 0, pmb = 0;
#pragma unroll
            for (int k = 0; k < 8; ++k) {
                float sv = bcast(h, kb + k);
                pra += sv * whr[k]; pza += sv * whz[k];
                pna += sv * whn[k]; pma += sv * wmv[k];
            }
#pragma unroll
            for (int k = 8; k < KW; ++k) {
                float sv = bcast(h, kb + k);
                prb += sv * whr[k]; pzb += sv * whz[k];
                pnb += sv * whn[k]; pmb += sv * wmv[k];
            }
            const int bufp = s & 1;
            part[bufp][0][sm][ws][lane] = pr + pra + prb;
            part[bufp][1][sm][ws][lane] = pz + pza + pzb;
            part[bufp][2][sm][ws][lane] = px;
            part[bufp][3][sm][ws][lane] = pna + pnb;
            part[bufp][4][sm][ws][lane] = pma + pmb;
            // stage next group's inputs just before the group's last barrier
            if (s == GS - 1 && do_ld) inbuf[(g + 1) & 1][sm2][lt] = ld;
            __syncthreads();

            // ---- post-barrier: reduce + nonlinearity (redundant per wave) ----
            float ar = b_r, az = b_z, ax = bx_n, ah = bh_n;
#pragma unroll
            for (int ww = 0; ww < WV; ++ww) {
                ar += part[bufp][0][sm][ww][lane];
                az += part[bufp][1][sm][ww][lane];
                ax += part[bufp][2][sm][ww][lane];
                ah += part[bufp][3][sm][ww][lane];
            }
            if (ws == 0) {  // amv for output t-1 (one wave per sample)
                float amv = part[bufp][4][sm][0][lane] + part[bufp][4][sm][1][lane]
                          + part[bufp][4][sm][2][lane] + part[bufp][4][sm][3][lane];
                if (lane < DIN && !(g == 0 && s == 0)) {
                    const int tm1 = 8 * g + s - 1;
                    obuf[(tm1 >> 3) & 1][sm][(tm1 & 7) * DIN + lane] = amv;
                }
            }
            // flush previous output group (slot 7 stashed post-s==0-barrier,
            // ordered by the s==1 barrier)
            if (s == 1 && g >= 1 && stg)
                obase[(size_t)(g - 1) * 160 + lt] = obuf[(g - 1) & 1][sm2][lt];

            float r = rcpf(1.0f + __expf(-ar));
            float z = rcpf(1.0f + __expf(-az));
            float pre = ax + r * ah;
            float e2 = __expf(2.0f * pre);       // inf-safe: nn -> +/-1
            float nn = 1.0f - 2.0f * rcpf(e2 + 1.0f);
            h = nn + z * (h - nn);
        }
    }

    // epilogue: output 999 from h_999, then flush output group 124
    {
        float pma = 0, pmb = 0;
#pragma unroll
        for (int k = 0; k < 8; ++k) pma += bcast(h, kb + k) * wmv[k];
#pragma unroll
        for (int k = 8; k < KW; ++k) pmb += bcast(h, kb + k) * wmv[k];
        part[0][4][sm][ws][lane] = pma + pmb;
        __syncthreads();
        if (ws == 0 && lane < DIN) {
            float amv = part[0][4][sm][0][lane] + part[0][4][sm][1][lane]
                      + part[0][4][sm][2][lane] + part[0][4][sm][3][lane];
            obuf[0][sm][7 * DIN + lane] = amv;  // t=999: group 124 slot 7 buf 0
        }
        __syncthreads();
        if (stg)
            obase[(size_t)(NG - 1) * 160 + lt] = obuf[0][sm2][lt];
    }
}

// ---------------- d_out init: the constant term ----------------------------
__global__ void init_out(float* out) {
    // -0.5*NO*T*log(2pi) / (T*NO) = -0.5*log(2pi)
    out[0] = -0.918938533204672742f;
}

// ---------------- Phase 2: per-(n,t) Gaussian log-lik ----------------------
__global__ __launch_bounds__(256)
void lik_phase2(const float* __restrict__ Yi, const float* __restrict__ Cw,
                const float* __restrict__ Hm, const float* __restrict__ mu_w,
                const float* __restrict__ b_mu, const float* __restrict__ b_var,
                const float* __restrict__ mv_in, float* __restrict__ out) {
    __shared__ float sH[NO * NS];
    __shared__ float smw[NO], sbm[NS], sbv[NS];
    __shared__ float ssum[4];
    const int tid = threadIdx.x;
    if (tid < NO * NS) sH[tid] = Hm[tid];
    if (tid < NO) smw[tid] = mu_w[tid];
    if (tid < NS) { sbm[tid] = b_mu[tid]; sbv[tid] = b_var[tid]; }
    __syncthreads();

    const int gid = blockIdx.x * 256 + tid;   // 0 .. BN*TT-1
    float contrib = 0.0f;
    if (gid < BN * TT) {
        const int n = gid / TT;
        const float* mv = mv_in + (size_t)gid * DIN;
        float mu[NS], va[NS];
#pragma unroll
        for (int i = 0; i < NS; ++i) {
            mu[i] = mv[i] + sbm[i];
            float x = mv[NS + i] + sbv[i];
            va[i] = (x > 0.0f) ? (x + log1pf(__expf(-x))) : log1pf(__expf(x));
        }
        const float* y = Yi + (size_t)gid * NO;
        float e[NO];
#pragma unroll
        for (int i = 0; i < NO; ++i) {
            float m = smw[i];
#pragma unroll
            for (int j = 0; j < NS; ++j) m += sH[i * NS + j] * mu[j];
            e[i] = y[i] - m;
        }
        // M = H diag(va) H^T + Cw (lower triangle only)
        float M[NO][NO];
        const float* cw = Cw + (size_t)n * NO * NO;
#pragma unroll
        for (int i = 0; i < NO; ++i)
#pragma unroll
            for (int j = 0; j <= i; ++j) M[i][j] = cw[i * NO + j];
#pragma unroll
        for (int l = 0; l < NS; ++l) {
            float vl = va[l];
            float hv[NO];
#pragma unroll
            for (int i = 0; i < NO; ++i) hv[i] = sH[i * NS + l];
#pragma unroll
            for (int i = 0; i < NO; ++i) {
                float hvi = hv[i] * vl;
#pragma unroll
                for (int j = 0; j <= i; ++j) M[i][j] += hvi * hv[j];
            }
        }
        // in-place Cholesky (lower), logdet = sum log d_j
        float logdet = 0.0f;
#pragma unroll
        for (int j = 0; j < NO; ++j) {
            float d = M[j][j];
#pragma unroll
            for (int k = 0; k < j; ++k) d -= M[j][k] * M[j][k];
            logdet += __logf(d);
            float s = sqrtf(d);
            M[j][j] = s;
            float inv = 1.0f / s;
#pragma unroll
            for (int i = j + 1; i < NO; ++i) {
                float v = M[i][j];
#pragma unroll
                for (int k = 0; k < j; ++k) v -= M[i][k] * M[j][k];
                M[i][j] = v * inv;
            }
        }
        // quad = || L^-1 e ||^2 (forward solve)
        float wv[NO];
        float quad = 0.0f;
#pragma unroll
        for (int i = 0; i < NO; ++i) {
            float v = e[i];
#pragma unroll
            for (int k = 0; k < i; ++k) v -= M[i][k] * wv[k];
            wv[i] = v / M[i][i];
            quad += wv[i] * wv[i];
        }
        const float SCALE = 0.5f / ((float)BN * (float)TT * (float)NO);
        contrib = -(logdet + quad) * SCALE;
    }

    // block reduction: wave shuffle, LDS across 4 waves, one atomic
#pragma unroll
    for (int off = 32; off > 0; off >>= 1) contrib += __shfl_down(contrib, off);
    if ((tid & 63) == 0) ssum[tid >> 6] = contrib;
    __syncthreads();
    if (tid == 0) {
        float s = ssum[0] + ssum[1] + ssum[2] + ssum[3];
        atomicAdd(out, s);
    }
}

// ---------------- launch ---------------------------------------------------
extern "C" void kernel_launch(void* const* d_in, const int* in_sizes, int n_in,
                              void* d_out, int out_size, void* d_ws, size_t ws_size,
                              hipStream_t stream) {
    const float* Yi    = (const float*)d_in[0];
    const float* Xh    = (const float*)d_in[1];
    const float* Cw    = (const float*)d_in[2];
    const float* Hm    = (const float*)d_in[3];
    const float* mu_w  = (const float*)d_in[4];
    const float* Wi    = (const float*)d_in[5];
    const float* Wh    = (const float*)d_in[6];
    const float* bi    = (const float*)d_in[7];
    const float* bh    = (const float*)d_in[8];
    const float* W_mu  = (const float*)d_in[9];
    const float* b_mu  = (const float*)d_in[10];
    const float* W_var = (const float*)d_in[11];
    const float* b_var = (const float*)d_in[12];
    float* out = (float*)d_out;
    float* mv  = (float*)d_ws;   // [BN*TT*DIN] floats = 20.48 MB

    init_out<<<1, 1, 0, stream>>>(out);
    gru_phase1<<<dim3(BN / SMP), dim3(512), 0, stream>>>(Yi, Xh, Wi, Wh, bi, bh,
                                                         W_mu, W_var, mv);
    lik_phase2<<<dim3((BN * TT + 255) / 256), dim3(256), 0, stream>>>(
        Yi, Cw, Hm, mu_w, b_mu, b_var, mv, out);
}

// Round 5
// 809.243 us; speedup vs baseline: 1.0952x; 1.0952x over previous
//
#include <hip/hip_runtime.h>
#include <math.h>

// Problem constants (fixed by the reference)
#define BN 256     // batch N
#define TT 1000    // timesteps
#define NO 10      // obs dim
#define NS 10      // state dim
#define HID 64     // GRU hidden
#define DIN 20     // NO + NS
#define G3 192     // 3*HID
#define WVS 8      // waves per sample (k-split)
#define KW 8       // HID / WVS
#define GS 8       // steps per group (1000 = 125 * 8)
#define NG 125     // groups

// broadcast lane `l`'s value of v to all lanes (l wave-uniform)
__device__ __forceinline__ float bcast(float v, int l) {
    return __int_as_float(__builtin_amdgcn_readlane(__float_as_int(v), l));
}
__device__ __forceinline__ float rcpf(float x) { return __builtin_amdgcn_rcpf(x); }

// Workgroup barrier WITHOUT the vmcnt(0) drain __syncthreads() emits.
// LDS ordering is guaranteed by the explicit lgkmcnt(0); global loads issued
// before the barrier stay in flight (their vmcnt wait lands at the register
// use point). The "memory" clobber pins all memory ops on both sides.
__device__ __forceinline__ void sync_lds() {
    asm volatile("s_waitcnt lgkmcnt(0)\n\ts_barrier" ::: "memory");
}

// ---------------- Phase 1: GRU recurrence ----------------------------------
// One sample per block; 8 waves, k-split 8 (wave w owns k in [8w,8w+8) of the
// hidden projection + 2-3 input dims). 2 waves/SIMD. Persistent weights are
// ~45 floats/lane -> fully register-resident (R3/R4's 79/lane overflowed the
// allocator's budget and shuttled through AGPRs/scratch, inflating issue 2x).
// All global I/O batched per 8-step group through LDS; raw lgkmcnt-only
// barriers keep the group prefetch load in flight across the step barriers.
__global__
__attribute__((amdgpu_flat_work_group_size(512, 512), amdgpu_waves_per_eu(2, 2)))
void gru_phase1(const float* __restrict__ Yi, const float* __restrict__ Xh,
                const float* __restrict__ Wi, const float* __restrict__ Wh,
                const float* __restrict__ bi, const float* __restrict__ bh,
                const float* __restrict__ Wmu, const float* __restrict__ Wvar,
                float* __restrict__ mv_out) {
    const int tid = threadIdx.x;
    const int lane = tid & 63;      // hidden unit index
    const int w = tid >> 6;         // wave id 0..7
    const int kb = w * KW;          // k-range base (hidden)

    // partials: [buf][acc][wave][lane]; accs 0=r 1=z 2=nx 3=nh 4=mv (10 KB)
    __shared__ float part[2][5][WVS][HID];
    // input staging: per group 160 floats = [y(8 steps x 10) | x(8 steps x 10)]
    __shared__ float inbuf[2][GS * DIN];
    // output staging: per group 160 floats = [step][20]
    __shared__ float obuf[2][GS * DIN];

    const int n = blockIdx.x;
    const float* ybase = Yi + (size_t)n * TT * NO;
    const float* xbase = Xh + (size_t)n * TT * NS;
    float* obase = mv_out + (size_t)n * TT * DIN;

    // this wave's input dims: waves 0-3 get 3 dims (0..11), 4-7 get 2 (12..19)
    const int dn = (w < 4) ? 3 : 2;
    const int d0 = (w < 4) ? 3 * w : 12 + 2 * (w - 4);
    // LDS offset within a step row for dim d: d<10 -> d ; d>=10 -> 70+d
    const int ib0 = (d0 < 10) ? d0 : 70 + d0;
    const int ib1 = (d0 + 1 < 10) ? d0 + 1 : 71 + d0;
    const int ib2 = (dn == 3) ? ((d0 + 2 < 10) ? d0 + 2 : 72 + d0) : ib0;

    // ---- per-lane weight slices (all register-resident) ----
    float whr[KW], whz[KW], whn[KW], wmv[KW];
#pragma unroll
    for (int k = 0; k < KW; ++k) {
        const int kk = kb + k;
        whr[k] = Wh[kk * G3 + lane];
        whz[k] = Wh[kk * G3 + 64 + lane];
        whn[k] = Wh[kk * G3 + 128 + lane];
        float wm = (lane < NS) ? Wmu[kk * NS + lane] : 0.0f;
        float wv = (lane >= NS && lane < 2 * NS) ? Wvar[kk * NS + (lane - NS)] : 0.0f;
        wmv[k] = wm + wv;   // packed: lanes 0..9 -> W_mu, lanes 10..19 -> W_var
    }
    const float wir0 = Wi[d0 * G3 + lane];
    const float wiz0 = Wi[d0 * G3 + 64 + lane];
    const float win0 = Wi[d0 * G3 + 128 + lane];
    const float wir1 = Wi[(d0 + 1) * G3 + lane];
    const float wiz1 = Wi[(d0 + 1) * G3 + 64 + lane];
    const float win1 = Wi[(d0 + 1) * G3 + 128 + lane];
    const float wir2 = (dn == 3) ? Wi[(d0 + 2) * G3 + lane] : 0.0f;
    const float wiz2 = (dn == 3) ? Wi[(d0 + 2) * G3 + 64 + lane] : 0.0f;
    const float win2 = (dn == 3) ? Wi[(d0 + 2) * G3 + 128 + lane] : 0.0f;

    const float b_r  = bi[lane] + bh[lane];
    const float b_z  = bi[64 + lane] + bh[64 + lane];
    const float bx_n = bi[128 + lane];
    const float bh_n = bh[128 + lane];

    // prologue: stage group 0
    if (tid < 160)
        inbuf[0][tid] = (tid < 80) ? ybase[tid] : xbase[tid - 80];
    sync_lds();

    float h = 0.0f;

#pragma unroll 1
    for (int g = 0; g < NG; ++g) {
        // next group's coalesced load; stays in flight across the barriers
        float ld = 0.0f;
        const bool do_ld = (tid < 160) && (g + 1 < NG);
        if (do_ld)
            ld = (tid < 80) ? ybase[(size_t)(g + 1) * 80 + tid]
                            : xbase[(size_t)(g + 1) * 80 + (tid - 80)];
        const float* ib = inbuf[g & 1];

#pragma unroll
        for (int s = 0; s < GS; ++s) {
            // ---- pre-barrier: partial sums ----
            const float x0 = ib[ib0 + 10 * s];
            const float x1 = ib[ib1 + 10 * s];
            const float x2 = ib[ib2 + 10 * s];      // weight 0 if dn==2
            float pr = x0 * wir0, pz = x0 * wiz0, px = x0 * win0;
            pr = fmaf(x1, wir1, pr); pz = fmaf(x1, wiz1, pz); px = fmaf(x1, win1, px);
            pr = fmaf(x2, wir2, pr); pz = fmaf(x2, wiz2, pz); px = fmaf(x2, win2, px);
            float pna = 0.0f, pma = 0.0f;
#pragma unroll
            for (int k = 0; k < KW; ++k) {
                float sv = bcast(h, kb + k);
                pr  = fmaf(sv, whr[k], pr);
                pz  = fmaf(sv, whz[k], pz);
                pna = fmaf(sv, whn[k], pna);
                pma = fmaf(sv, wmv[k], pma);
            }
            const int bufp = s & 1;
            part[bufp][0][w][lane] = pr;
            part[bufp][1][w][lane] = pz;
            part[bufp][2][w][lane] = px;
            part[bufp][3][w][lane] = pna;
            part[bufp][4][w][lane] = pma;
            // stage next group's inputs just before the group's last barrier
            if (s == GS - 1 && do_ld) inbuf[(g + 1) & 1][tid] = ld;
            sync_lds();

            // ---- post-barrier: reduce + nonlinearity (redundant per wave) ----
            float ar = b_r, az = b_z, ax = bx_n, ah = bh_n;
#pragma unroll
            for (int ww = 0; ww < WVS; ++ww) {
                ar += part[bufp][0][ww][lane];
                az += part[bufp][1][ww][lane];
                ax += part[bufp][2][ww][lane];
                ah += part[bufp][3][ww][lane];
            }
            if (w == 7) {   // amv for output t-1 (wave 7: lightest input load)
                float amv = 0.0f;
#pragma unroll
                for (int ww = 0; ww < WVS; ++ww) amv += part[bufp][4][ww][lane];
                if (lane < DIN && !(g == 0 && s == 0)) {
                    const int tm1 = 8 * g + s - 1;
                    obuf[(tm1 >> 3) & 1][(tm1 & 7) * DIN + lane] = amv;
                }
            }
            // flush previous output group (slot 7 stashed post-s==0-barrier,
            // ordered by the s==1 barrier)
            if (s == 1 && g >= 1 && tid < 160)
                obase[(size_t)(g - 1) * 160 + tid] = obuf[(g - 1) & 1][tid];

            float r = rcpf(1.0f + __expf(-ar));
            float z = rcpf(1.0f + __expf(-az));
            float pre = ax + r * ah;
            float e2 = __expf(2.0f * pre);       // inf-safe: nn -> +/-1
            float nn = 1.0f - 2.0f * rcpf(e2 + 1.0f);
            h = nn + z * (h - nn);
        }
    }

    // epilogue: output 999 from h_999, then flush output group 124
    {
        float pma = 0.0f;
#pragma unroll
        for (int k = 0; k < KW; ++k) pma = fmaf(bcast(h, kb + k), wmv[k], pma);
        part[0][4][w][lane] = pma;   // no reader of part[0][4] remains in-loop
        sync_lds();
        if (w == 7 && lane < DIN) {
            float amv = 0.0f;
#pragma unroll
            for (int ww = 0; ww < WVS; ++ww) amv += part[0][4][ww][lane];
            obuf[0][7 * DIN + lane] = amv;  // t=999: group 124, slot 7, buf 0
        }
        sync_lds();
        if (tid < 160)
            obase[(size_t)(NG - 1) * 160 + tid] = obuf[0][tid];
    }
}

// ---------------- d_out init: the constant term ----------------------------
__global__ void init_out(float* out) {
    // -0.5*NO*T*log(2pi) / (T*NO) = -0.5*log(2pi)
    out[0] = -0.918938533204672742f;
}

// ---------------- Phase 2: per-(n,t) Gaussian log-lik ----------------------
__global__ __launch_bounds__(256)
void lik_phase2(const float* __restrict__ Yi, const float* __restrict__ Cw,
                const float* __restrict__ Hm, const float* __restrict__ mu_w,
                const float* __restrict__ b_mu, const float* __restrict__ b_var,
                const float* __restrict__ mv_in, float* __restrict__ out) {
    __shared__ float sH[NO * NS];
    __shared__ float smw[NO], sbm[NS], sbv[NS];
    __shared__ float ssum[4];
    const int tid = threadIdx.x;
    if (tid < NO * NS) sH[tid] = Hm[tid];
    if (tid < NO) smw[tid] = mu_w[tid];
    if (tid < NS) { sbm[tid] = b_mu[tid]; sbv[tid] = b_var[tid]; }
    __syncthreads();

    const int gid = blockIdx.x * 256 + tid;   // 0 .. BN*TT-1
    float contrib = 0.0f;
    if (gid < BN * TT) {
        const int n = gid / TT;
        const float* mv = mv_in + (size_t)gid * DIN;
        float mu[NS], va[NS];
#pragma unroll
        for (int i = 0; i < NS; ++i) {
            mu[i] = mv[i] + sbm[i];
            float x = mv[NS + i] + sbv[i];
            va[i] = (x > 0.0f) ? (x + log1pf(__expf(-x))) : log1pf(__expf(x));
        }
        const float* y = Yi + (size_t)gid * NO;
        float e[NO];
#pragma unroll
        for (int i = 0; i < NO; ++i) {
            float m = smw[i];
#pragma unroll
            for (int j = 0; j < NS; ++j) m = fmaf(sH[i * NS + j], mu[j], m);
            e[i] = y[i] - m;
        }
        // M = H diag(va) H^T + Cw (lower triangle only)
        float M[NO][NO];
        const float* cw = Cw + (size_t)n * NO * NO;
#pragma unroll
        for (int i = 0; i < NO; ++i)
#pragma unroll
            for (int j = 0; j <= i; ++j) M[i][j] = cw[i * NO + j];
#pragma unroll
        for (int l = 0; l < NS; ++l) {
            float vl = va[l];
            float hv[NO];
#pragma unroll
            for (int i = 0; i < NO; ++i) hv[i] = sH[i * NS + l];
#pragma unroll
            for (int i = 0; i < NO; ++i) {
                float hvi = hv[i] * vl;
#pragma unroll
                for (int j = 0; j <= i; ++j) M[i][j] = fmaf(hvi, hv[j], M[i][j]);
            }
        }
        // in-place Cholesky (lower); fast rsqrt/rcp (error ~1ulp, harmless
        // vs the 3.1e-2 threshold on an averaged scalar)
        float logdet = 0.0f;
        float drs[NO];                  // 1/sqrt(d_j) for the forward solve
#pragma unroll
        for (int j = 0; j < NO; ++j) {
            float d = M[j][j];
#pragma unroll
            for (int k = 0; k < j; ++k) d = fmaf(-M[j][k], M[j][k], d);
            logdet += __logf(d);
            float rs = __frsqrt_rn(d);
            drs[j] = rs;
            M[j][j] = d * rs;           // sqrt(d)
#pragma unroll
            for (int i = j + 1; i < NO; ++i) {
                float v = M[i][j];
#pragma unroll
                for (int k = 0; k < j; ++k) v = fmaf(-M[i][k], M[j][k], v);
                M[i][j] = v * rs;
            }
        }
        // quad = || L^-1 e ||^2 (forward solve)
        float wv[NO];
        float quad = 0.0f;
#pragma unroll
        for (int i = 0; i < NO; ++i) {
            float v = e[i];
#pragma unroll
            for (int k = 0; k < i; ++k) v = fmaf(-M[i][k], wv[k], v);
            wv[i] = v * drs[i] * rcpf(M[i][i] * drs[i]);  // v / M[i][i]
            quad = fmaf(wv[i], wv[i], quad);
        }
        const float SCALE = 0.5f / ((float)BN * (float)TT * (float)NO);
        contrib = -(logdet + quad) * SCALE;
    }

    // block reduction: wave shuffle, LDS across 4 waves, one atomic
#pragma unroll
    for (int off = 32; off > 0; off >>= 1) contrib += __shfl_down(contrib, off);
    if ((tid & 63) == 0) ssum[tid >> 6] = contrib;
    __syncthreads();
    if (tid == 0) {
        float s = ssum[0] + ssum[1] + ssum[2] + ssum[3];
        atomicAdd(out, s);
    }
}

// ---------------- launch ---------------------------------------------------
extern "C" void kernel_launch(void* const* d_in, const int* in_sizes, int n_in,
                              void* d_out, int out_size, void* d_ws, size_t ws_size,
                              hipStream_t stream) {
    const float* Yi    = (const float*)d_in[0];
    const float* Xh    = (const float*)d_in[1];
    const float* Cw    = (const float*)d_in[2];
    const float* Hm    = (const float*)d_in[3];
    const float* mu_w  = (const float*)d_in[4];
    const float* Wi    = (const float*)d_in[5];
    const float* Wh    = (const float*)d_in[6];
    const float* bi    = (const float*)d_in[7];
    const float* bh    = (const float*)d_in[8];
    const float* W_mu  = (const float*)d_in[9];
    const float* b_mu  = (const float*)d_in[10];
    const float* W_var = (const float*)d_in[11];
    const float* b_var = (const float*)d_in[12];
    float* out = (float*)d_out;
    float* mv  = (float*)d_ws;   // [BN*TT*DIN] floats = 20.48 MB

    init_out<<<1, 1, 0, stream>>>(out);
    gru_phase1<<<dim3(BN), dim3(512), 0, stream>>>(Yi, Xh, Wi, Wh, bi, bh,
                                                   W_mu, W_var, mv);
    lik_phase2<<<dim3((BN * TT + 255) / 256), dim3(256), 0, stream>>>(
        Yi, Cw, Hm, mu_w, b_mu, b_var, mv, out);
}

// Round 6
// 590.644 us; speedup vs baseline: 1.5005x; 1.3701x over previous
//
#include <hip/hip_runtime.h>
#include <math.h>

// Problem constants (fixed by the reference)
#define BN 256     // batch N
#define TT 1000    // timesteps
#define NO 10      // obs dim
#define NS 10      // state dim
#define HID 64     // GRU hidden
#define DIN 20     // NO + NS
#define G3 192     // 3*HID
#define WV 4       // waves per sample (k-split)
#define KW 16      // HID / WV
#define GS 8       // steps per group (1000 = 125 * 8)
#define NG 125     // groups

// broadcast lane `l`'s value of v to all lanes (l wave-uniform)
__device__ __forceinline__ float bcast(float v, int l) {
    return __int_as_float(__builtin_amdgcn_readlane(__float_as_int(v), l));
}
__device__ __forceinline__ float rcpf(float x) { return __builtin_amdgcn_rcpf(x); }

// Workgroup barrier WITHOUT the vmcnt(0) drain __syncthreads() emits.
// LDS ordering needs only lgkmcnt(0); global loads/stores issued before the
// barrier stay in flight (their vmcnt wait lands at the register use point,
// or never, for stores).
__device__ __forceinline__ void sync_lds() {
    asm volatile("s_waitcnt lgkmcnt(0)\n\ts_barrier" ::: "memory");
}

// ---------------- Phase 1: GRU recurrence ----------------------------------
// One sample per block, 4 waves (1/SIMD), k-split: wave w owns k in
// [16w,16w+16) of the hidden projection and input dims [5w,5w+5).
// R5 lesson: the post-barrier cost is the synchronized LDS read burst, which
// scales with waves x reads/wave. So: 4 waves (not 8), and the 4 exchanged
// accumulators (r,z,nx,nh) packed as float4 -> 1 ds_write_b128 + 4
// ds_read_b128 per wave per step. amv partials are a separate b32 array
// reduced by wave 3 only.
// waves_per_eu(1,1): 512-VGPR budget, guarantees the 79 persistent floats
// stay register-resident (R3's 72-VGPR AGPR-parking trap).
__global__
__attribute__((amdgpu_flat_work_group_size(256, 256), amdgpu_waves_per_eu(1, 1)))
void gru_phase1(const float* __restrict__ Yi, const float* __restrict__ Xh,
                const float* __restrict__ Wi, const float* __restrict__ Wh,
                const float* __restrict__ bi, const float* __restrict__ bh,
                const float* __restrict__ Wmu, const float* __restrict__ Wvar,
                float* __restrict__ mv_out) {
    const int tid = threadIdx.x;
    const int lane = tid & 63;      // hidden unit index
    const int w = tid >> 6;         // wave id 0..3
    const int kb = w * KW;          // k-range base (hidden)

    // packed partials: [buf][wave][lane] = {r, z, nx, nh}  (8 KB)
    __shared__ float4 part[2][WV][HID];
    // amv partials (separate, reduced by wave 3 only)      (2 KB)
    __shared__ float pamv[2][WV][HID];
    // input staging: per group 160 floats = [y(8x10) | x(8x10)]
    __shared__ float inbuf[2][GS * DIN];
    // output staging: per group 160 floats = [step][20]
    __shared__ float obuf[2][GS * DIN];

    const int n = blockIdx.x;
    const float* ybase = Yi + (size_t)n * TT * NO;
    const float* xbase = Xh + (size_t)n * TT * NS;
    float* obase = mv_out + (size_t)n * TT * DIN;

    // ---- per-lane weight slices (all register-resident) ----
    float whr[KW], whz[KW], whn[KW], wmv[KW];
    float wir[5], wiz[5], win[5];
#pragma unroll
    for (int k = 0; k < KW; ++k) {
        const int kk = kb + k;
        whr[k] = Wh[kk * G3 + lane];
        whz[k] = Wh[kk * G3 + 64 + lane];
        whn[k] = Wh[kk * G3 + 128 + lane];
        float wm = (lane < NS) ? Wmu[kk * NS + lane] : 0.0f;
        float wv = (lane >= NS && lane < 2 * NS) ? Wvar[kk * NS + (lane - NS)] : 0.0f;
        wmv[k] = wm + wv;   // packed: lanes 0..9 -> W_mu, lanes 10..19 -> W_var
    }
#pragma unroll
    for (int k = 0; k < 5; ++k) {
        const int d = 5 * w + k;    // this wave's input dims
        wir[k] = Wi[d * G3 + lane];
        wiz[k] = Wi[d * G3 + 64 + lane];
        win[k] = Wi[d * G3 + 128 + lane];
    }
    const float b_r  = bi[lane] + bh[lane];
    const float b_z  = bi[64 + lane] + bh[64 + lane];
    const float bx_n = bi[128 + lane];
    const float bh_n = bh[128 + lane];

    // LDS offset of this wave's 5 input dims within a step row
    const int ibase = ((w >= 2) ? 80 : 0) + (w & 1) * 5;

    // prologue: stage group 0
    if (tid < 160)
        inbuf[0][tid] = (tid < 80) ? ybase[tid] : xbase[tid - 80];
    sync_lds();

    float h = 0.0f;

#pragma unroll 1
    for (int g = 0; g < NG; ++g) {
        // next group's coalesced load; stays in flight across the barriers
        float ld = 0.0f;
        const bool do_ld = (tid < 160) && (g + 1 < NG);
        if (do_ld)
            ld = (tid < 80) ? ybase[(size_t)(g + 1) * 80 + tid]
                            : xbase[(size_t)(g + 1) * 80 + (tid - 80)];
        const float* ib = inbuf[g & 1];

#pragma unroll
        for (int s = 0; s < GS; ++s) {
            // ---- pre-barrier: partial sums from h (= h_{t-1}, t = 8g+s) ----
            const int ro = ibase + 10 * s;
            const float x0 = ib[ro], x1 = ib[ro + 1], x2 = ib[ro + 2];
            const float x3 = ib[ro + 3], x4 = ib[ro + 4];
            float pr = x0 * wir[0], pz = x0 * wiz[0], px = x0 * win[0];
            pr = fmaf(x1, wir[1], pr); pz = fmaf(x1, wiz[1], pz); px = fmaf(x1, win[1], px);
            pr = fmaf(x2, wir[2], pr); pz = fmaf(x2, wiz[2], pz); px = fmaf(x2, win[2], px);
            pr = fmaf(x3, wir[3], pr); pz = fmaf(x3, wiz[3], pz); px = fmaf(x3, win[3], px);
            pr = fmaf(x4, wir[4], pr); pz = fmaf(x4, wiz[4], pz); px = fmaf(x4, win[4], px);
            float pn = 0.0f, pm = 0.0f;
#pragma unroll
            for (int k = 0; k < KW; ++k) {
                float sv = bcast(h, kb + k);
                pr = fmaf(sv, whr[k], pr);
                pz = fmaf(sv, whz[k], pz);
                pn = fmaf(sv, whn[k], pn);
                pm = fmaf(sv, wmv[k], pm);
            }
            const int bufp = s & 1;
            part[bufp][w][lane] = make_float4(pr, pz, px, pn);  // ds_write_b128
            pamv[bufp][w][lane] = pm;
            // stage next group's inputs just before the group's last barrier
            if (s == GS - 1 && do_ld) inbuf[(g + 1) & 1][tid] = ld;
            sync_lds();

            // ---- post-barrier: reduce (4x ds_read_b128) + nonlinearity ----
            const float4 q0 = part[bufp][0][lane];
            const float4 q1 = part[bufp][1][lane];
            const float4 q2 = part[bufp][2][lane];
            const float4 q3 = part[bufp][3][lane];
            const float ar = b_r  + ((q0.x + q1.x) + (q2.x + q3.x));
            const float az = b_z  + ((q0.y + q1.y) + (q2.y + q3.y));
            const float ax = bx_n + ((q0.z + q1.z) + (q2.z + q3.z));
            const float ah = bh_n + ((q0.w + q1.w) + (q2.w + q3.w));
            if (w == 3) {   // amv for output t-1
                float amv = (pamv[bufp][0][lane] + pamv[bufp][1][lane])
                          + (pamv[bufp][2][lane] + pamv[bufp][3][lane]);
                if (lane < DIN && !(g == 0 && s == 0)) {
                    const int tm1 = 8 * g + s - 1;
                    obuf[(tm1 >> 3) & 1][(tm1 & 7) * DIN + lane] = amv;
                }
            }
            // flush previous output group (slot 7 stashed post-s==0-barrier,
            // ordered by the s==1 barrier); store stays in flight (no vmcnt)
            if (s == 1 && g >= 1 && tid < 160)
                obase[(size_t)(g - 1) * 160 + tid] = obuf[(g - 1) & 1][tid];

            float r = rcpf(1.0f + __expf(-ar));
            float z = rcpf(1.0f + __expf(-az));
            float pre = fmaf(r, ah, ax);
            float e2 = __expf(2.0f * pre);       // inf-safe: nn -> +/-1
            float nn = 1.0f - 2.0f * rcpf(e2 + 1.0f);
            h = fmaf(z, h - nn, nn);             // (1-z)*n + z*h
        }
    }

    // epilogue: output 999 from h_999, then flush output group 124
    {
        float pm = 0.0f;
#pragma unroll
        for (int k = 0; k < KW; ++k) pm = fmaf(bcast(h, kb + k), wmv[k], pm);
        pamv[0][w][lane] = pm;      // buf 0: last read was t=998 (pre-s7 barrier)
        sync_lds();
        if (w == 3 && lane < DIN) {
            float amv = (pamv[0][0][lane] + pamv[0][1][lane])
                      + (pamv[0][2][lane] + pamv[0][3][lane]);
            obuf[0][7 * DIN + lane] = amv;  // t=999: group 124, slot 7, buf 0
        }
        sync_lds();
        if (tid < 160)
            obase[(size_t)(NG - 1) * 160 + tid] = obuf[0][tid];
    }
}

// ---------------- d_out init: the constant term ----------------------------
__global__ void init_out(float* out) {
    // -0.5*NO*T*log(2pi) / (T*NO) = -0.5*log(2pi)
    out[0] = -0.918938533204672742f;
}

// ---------------- Phase 2: per-(n,t) Gaussian log-lik ----------------------
__global__ __launch_bounds__(256)
void lik_phase2(const float* __restrict__ Yi, const float* __restrict__ Cw,
                const float* __restrict__ Hm, const float* __restrict__ mu_w,
                const float* __restrict__ b_mu, const float* __restrict__ b_var,
                const float* __restrict__ mv_in, float* __restrict__ out) {
    __shared__ float sH[NO * NS];
    __shared__ float smw[NO], sbm[NS], sbv[NS];
    __shared__ float ssum[4];
    const int tid = threadIdx.x;
    if (tid < NO * NS) sH[tid] = Hm[tid];
    if (tid < NO) smw[tid] = mu_w[tid];
    if (tid < NS) { sbm[tid] = b_mu[tid]; sbv[tid] = b_var[tid]; }
    __syncthreads();

    const int gid = blockIdx.x * 256 + tid;   // 0 .. BN*TT-1
    float contrib = 0.0f;
    if (gid < BN * TT) {
        const int n = gid / TT;
        const float* mv = mv_in + (size_t)gid * DIN;
        float mu[NS], va[NS];
#pragma unroll
        for (int i = 0; i < NS; ++i) {
            mu[i] = mv[i] + sbm[i];
            float x = mv[NS + i] + sbv[i];
            va[i] = (x > 0.0f) ? (x + log1pf(__expf(-x))) : log1pf(__expf(x));
        }
        const float* y = Yi + (size_t)gid * NO;
        float e[NO];
#pragma unroll
        for (int i = 0; i < NO; ++i) {
            float m = smw[i];
#pragma unroll
            for (int j = 0; j < NS; ++j) m = fmaf(sH[i * NS + j], mu[j], m);
            e[i] = y[i] - m;
        }
        // M = H diag(va) H^T + Cw (lower triangle only)
        float M[NO][NO];
        const float* cw = Cw + (size_t)n * NO * NO;
#pragma unroll
        for (int i = 0; i < NO; ++i)
#pragma unroll
            for (int j = 0; j <= i; ++j) M[i][j] = cw[i * NO + j];
#pragma unroll
        for (int l = 0; l < NS; ++l) {
            float vl = va[l];
            float hv[NO];
#pragma unroll
            for (int i = 0; i < NO; ++i) hv[i] = sH[i * NS + l];
#pragma unroll
            for (int i = 0; i < NO; ++i) {
                float hvi = hv[i] * vl;
#pragma unroll
                for (int j = 0; j <= i; ++j) M[i][j] = fmaf(hvi, hv[j], M[i][j]);
            }
        }
        // in-place Cholesky (lower); fast rsqrt/rcp (error ~1ulp, harmless
        // vs the 3.1e-2 threshold on an averaged scalar)
        float logdet = 0.0f;
        float drs[NO];                  // 1/sqrt(d_j) for the forward solve
#pragma unroll
        for (int j = 0; j < NO; ++j) {
            float d = M[j][j];
#pragma unroll
            for (int k = 0; k < j; ++k) d = fmaf(-M[j][k], M[j][k], d);
            logdet += __logf(d);
            float rs = __frsqrt_rn(d);
            drs[j] = rs;
            M[j][j] = d * rs;           // sqrt(d)
#pragma unroll
            for (int i = j + 1; i < NO; ++i) {
                float v = M[i][j];
#pragma unroll
                for (int k = 0; k < j; ++k) v = fmaf(-M[i][k], M[j][k], v);
                M[i][j] = v * rs;
            }
        }
        // quad = || L^-1 e ||^2 (forward solve)
        float wv[NO];
        float quad = 0.0f;
#pragma unroll
        for (int i = 0; i < NO; ++i) {
            float v = e[i];
#pragma unroll
            for (int k = 0; k < i; ++k) v = fmaf(-M[i][k], wv[k], v);
            wv[i] = v * drs[i] * rcpf(M[i][i] * drs[i]);  // v / M[i][i]
            quad = fmaf(wv[i], wv[i], quad);
        }
        const float SCALE = 0.5f / ((float)BN * (float)TT * (float)NO);
        contrib = -(logdet + quad) * SCALE;
    }

    // block reduction: wave shuffle, LDS across 4 waves, one atomic
#pragma unroll
    for (int off = 32; off > 0; off >>= 1) contrib += __shfl_down(contrib, off);
    if ((tid & 63) == 0) ssum[tid >> 6] = contrib;
    __syncthreads();
    if (tid == 0) {
        float s = ssum[0] + ssum[1] + ssum[2] + ssum[3];
        atomicAdd(out, s);
    }
}

// ---------------- launch ---------------------------------------------------
extern "C" void kernel_launch(void* const* d_in, const int* in_sizes, int n_in,
                              void* d_out, int out_size, void* d_ws, size_t ws_size,
                              hipStream_t stream) {
    const float* Yi    = (const float*)d_in[0];
    const float* Xh    = (const float*)d_in[1];
    const float* Cw    = (const float*)d_in[2];
    const float* Hm    = (const float*)d_in[3];
    const float* mu_w  = (const float*)d_in[4];
    const float* Wi    = (const float*)d_in[5];
    const float* Wh    = (const float*)d_in[6];
    const float* bi    = (const float*)d_in[7];
    const float* bh    = (const float*)d_in[8];
    const float* W_mu  = (const float*)d_in[9];
    const float* b_mu  = (const float*)d_in[10];
    const float* W_var = (const float*)d_in[11];
    const float* b_var = (const float*)d_in[12];
    float* out = (float*)d_out;
    float* mv  = (float*)d_ws;   // [BN*TT*DIN] floats = 20.48 MB

    init_out<<<1, 1, 0, stream>>>(out);
    gru_phase1<<<dim3(BN), dim3(256), 0, stream>>>(Yi, Xh, Wi, Wh, bi, bh,
                                                   W_mu, W_var, mv);
    lik_phase2<<<dim3((BN * TT + 255) / 256), dim3(256), 0, stream>>>(
        Yi, Cw, Hm, mu_w, b_mu, b_var, mv, out);
}